// Round 1
// baseline (3878.091 us; speedup 1.0000x reference)
//
#include <hip/hip_runtime.h>
#include <hip/hip_bf16.h>
#include <math.h>

#define N_NODESC 100000
#define N_EDGESC 300000
#define HIDC 128
#define EMBC 64
#define N_GRAPHSC 4096
#define DEG_CAP 32

// ---------------------------------------------------------------------------
// CSR build: deg[t][n] counts, csr[t][n][DEG_CAP] holds src lists (padded).
// ---------------------------------------------------------------------------
__global__ __launch_bounds__(256) void k_build_csr(const int* __restrict__ ei,
                                                   int* __restrict__ deg,
                                                   int* __restrict__ csr) {
    int id = blockIdx.x * 256 + threadIdx.x;
    if (id >= 3 * N_EDGESC) return;
    int t = id / N_EDGESC;
    int i = id - t * N_EDGESC;
    int src = ei[(t * 2 + 0) * N_EDGESC + i];
    int dst = ei[(t * 2 + 1) * N_EDGESC + i];
    int p = atomicAdd(&deg[t * N_NODESC + dst], 1);
    if (p < DEG_CAP) csr[(t * N_NODESC + dst) * DEG_CAP + p] = src;
}

// ---------------------------------------------------------------------------
// Wbig [512][256]: x=[m|h] (K=256) -> (Sr, Sz, In, Hn) (512 outputs).
//   rows   0..127 : [W_ih[c]     | W_hh[c]    ]   -> i_r + h_r
//   rows 128..255 : [W_ih[128+c] | W_hh[128+c]]   -> i_z + h_z
//   rows 256..383 : [W_ih[256+c] | 0          ]   -> i_n
//   rows 384..511 : [0           | W_hh[256+c]]   -> h_n
// ---------------------------------------------------------------------------
__global__ __launch_bounds__(256) void k_build_wbig(const float* __restrict__ W_ih,
                                                    const float* __restrict__ W_hh,
                                                    const float* __restrict__ b_ih,
                                                    const float* __restrict__ b_hh,
                                                    float* __restrict__ Wbig,
                                                    float* __restrict__ bbig) {
    int id = blockIdx.x * 256 + threadIdx.x;  // 512*256 total
    int j = id >> 8;
    int k = id & 255;
    int sec = j >> 7;
    int c = j & 127;
    float v = 0.f;
    if (k < 128) {
        if (sec == 0) v = W_ih[c * HIDC + k];
        else if (sec == 1) v = W_ih[(128 + c) * HIDC + k];
        else if (sec == 2) v = W_ih[(256 + c) * HIDC + k];
    } else {
        int kk = k - 128;
        if (sec == 0) v = W_hh[c * HIDC + kk];
        else if (sec == 1) v = W_hh[(128 + c) * HIDC + kk];
        else if (sec == 3) v = W_hh[(256 + c) * HIDC + kk];
    }
    Wbig[j * 256 + k] = v;
    if (k == 0) {
        float b;
        if (sec == 0) b = b_ih[c] + b_hh[c];
        else if (sec == 1) b = b_ih[128 + c] + b_hh[128 + c];
        else if (sec == 2) b = b_ih[256 + c];
        else b = b_hh[256 + c];
        bbig[j] = b;
    }
}

// ---------------------------------------------------------------------------
// A[n][c] = sum over edges (src->n, type t) of h[src][c].  2 nodes / block.
// ---------------------------------------------------------------------------
__global__ __launch_bounds__(256) void k_aggregate(const float* __restrict__ h,
                                                   const int* __restrict__ deg,
                                                   const int* __restrict__ csr,
                                                   float* __restrict__ A,
                                                   int t) {
    int n = blockIdx.x * 2 + (threadIdx.x >> 7);
    int c = threadIdx.x & 127;
    int d = deg[t * N_NODESC + n];
    if (d > DEG_CAP) d = DEG_CAP;
    const int* lst = &csr[(t * N_NODESC + n) * DEG_CAP];
    float acc = 0.f;
    for (int k = 0; k < d; k++) {
        int s = lst[k];
        acc += h[s * HIDC + c];
    }
    A[n * HIDC + c] = acc;
}

// ---------------------------------------------------------------------------
// m (+)= A @ W_t    (W_t is [k][j] row-major, K=128, J=128)
// 32 rows/block, 256 threads, 4x4 register tile per thread.
// ---------------------------------------------------------------------------
__global__ __launch_bounds__(256) void k_msg_gemm(const float* __restrict__ A,
                                                  const float* __restrict__ Wt,
                                                  float* __restrict__ m,
                                                  int accumulate) {
    __shared__ float As[32][132];   // padded: banks differ per row
    __shared__ float Ws[64][128];
    int tid = threadIdx.x;
    int row0 = blockIdx.x * 32;
    int rg = tid >> 5;   // 8 row-groups * 4 rows
    int cg = tid & 31;   // cols cg + {0,32,64,96}
    float acc[4][4];
#pragma unroll
    for (int r = 0; r < 4; r++)
#pragma unroll
        for (int c = 0; c < 4; c++) acc[r][c] = 0.f;

#pragma unroll
    for (int p = 0; p < 4; p++) {
        int idx = p * 256 + tid;
        int r = idx >> 5;
        int c4 = idx & 31;
        *(float4*)&As[r][c4 * 4] = *(const float4*)&A[(row0 + r) * HIDC + c4 * 4];
    }
    for (int kc = 0; kc < 128; kc += 64) {
        __syncthreads();
#pragma unroll
        for (int p = 0; p < 8; p++) {
            int idx = p * 256 + tid;
            int k = idx >> 5;
            int c4 = idx & 31;
            *(float4*)&Ws[k][c4 * 4] = *(const float4*)&Wt[(kc + k) * HIDC + c4 * 4];
        }
        __syncthreads();
#pragma unroll 8
        for (int k = 0; k < 64; k++) {
            float a[4], w[4];
#pragma unroll
            for (int r = 0; r < 4; r++) a[r] = As[rg * 4 + r][kc + k];
#pragma unroll
            for (int c = 0; c < 4; c++) w[c] = Ws[k][cg + 32 * c];
#pragma unroll
            for (int r = 0; r < 4; r++)
#pragma unroll
                for (int c = 0; c < 4; c++) acc[r][c] += a[r] * w[c];
        }
    }
#pragma unroll
    for (int r = 0; r < 4; r++) {
        int row = row0 + rg * 4 + r;
#pragma unroll
        for (int c = 0; c < 4; c++) {
            int o = row * HIDC + cg + 32 * c;
            m[o] = accumulate ? (m[o] + acc[r][c]) : acc[r][c];
        }
    }
}

// ---------------------------------------------------------------------------
// GRU: x=[m+msgbias | h] (K=256) -> 4 sections of 128 via Wbig, gates, h update.
// 16 rows/block, 256 threads, per section 4 rows x 2 cols per thread.
// ---------------------------------------------------------------------------
__global__ __launch_bounds__(256) void k_gru(const float* __restrict__ m,
                                             float* __restrict__ h,
                                             const int* __restrict__ deg,
                                             const float* __restrict__ b_msg,
                                             const float* __restrict__ Wbig,
                                             const float* __restrict__ bbig) {
    __shared__ float xs[16][260];
    __shared__ float Ws[32][129];
    int tid = threadIdx.x;
    int row0 = blockIdx.x * 16;
#pragma unroll
    for (int p = 0; p < 2; p++) {
        int idx = p * 256 + tid;
        int r = idx >> 5;
        int c4 = idx & 31;
        int row = row0 + r;
        float4 v = *(const float4*)&m[row * HIDC + c4 * 4];
        float d0 = (float)deg[row];
        float d1 = (float)deg[N_NODESC + row];
        float d2 = (float)deg[2 * N_NODESC + row];
        float4 b0 = *(const float4*)&b_msg[c4 * 4];
        float4 b1 = *(const float4*)&b_msg[HIDC + c4 * 4];
        float4 b2 = *(const float4*)&b_msg[2 * HIDC + c4 * 4];
        v.x += d0 * b0.x + d1 * b1.x + d2 * b2.x;
        v.y += d0 * b0.y + d1 * b1.y + d2 * b2.y;
        v.z += d0 * b0.z + d1 * b1.z + d2 * b2.z;
        v.w += d0 * b0.w + d1 * b1.w + d2 * b2.w;
        *(float4*)&xs[r][c4 * 4] = v;
        *(float4*)&xs[r][HIDC + c4 * 4] = *(const float4*)&h[row * HIDC + c4 * 4];
    }
    int rg = tid >> 6;   // 4 row-groups * 4 rows (wave-uniform -> broadcast reads)
    int cg = tid & 63;   // cols cg, cg+64
    float sAcc[4][4][2];
#pragma unroll
    for (int sec = 0; sec < 4; sec++) {
        float acc[4][2] = {{0.f, 0.f}, {0.f, 0.f}, {0.f, 0.f}, {0.f, 0.f}};
        for (int kc = 0; kc < 256; kc += 32) {
            __syncthreads();
#pragma unroll
            for (int p = 0; p < 4; p++) {
                int idx = p * 256 + tid;
                int j = idx >> 3;
                int q = idx & 7;
                float4 w = *(const float4*)&Wbig[(sec * 128 + j) * 256 + kc + q * 4];
                Ws[q * 4 + 0][j] = w.x;
                Ws[q * 4 + 1][j] = w.y;
                Ws[q * 4 + 2][j] = w.z;
                Ws[q * 4 + 3][j] = w.w;
            }
            __syncthreads();
#pragma unroll 8
            for (int k = 0; k < 32; k++) {
                float a[4];
#pragma unroll
                for (int r = 0; r < 4; r++) a[r] = xs[rg * 4 + r][kc + k];
                float w0 = Ws[k][cg];
                float w1 = Ws[k][cg + 64];
#pragma unroll
                for (int r = 0; r < 4; r++) {
                    acc[r][0] += a[r] * w0;
                    acc[r][1] += a[r] * w1;
                }
            }
        }
#pragma unroll
        for (int r = 0; r < 4; r++) {
            sAcc[sec][r][0] = acc[r][0];
            sAcc[sec][r][1] = acc[r][1];
        }
    }
#pragma unroll
    for (int r = 0; r < 4; r++) {
        int row = row0 + rg * 4 + r;
#pragma unroll
        for (int ci = 0; ci < 2; ci++) {
            int c = cg + ci * 64;
            float Sr = sAcc[0][r][ci] + bbig[c];
            float Sz = sAcc[1][r][ci] + bbig[128 + c];
            float In = sAcc[2][r][ci] + bbig[256 + c];
            float Hn = sAcc[3][r][ci] + bbig[384 + c];
            float hv = xs[rg * 4 + r][HIDC + c];
            float rr = 1.f / (1.f + expf(-Sr));
            float zz = 1.f / (1.f + expf(-Sz));
            float nn = tanhf(In + rr * Hn);
            h[row * HIDC + c] = (1.f - zz) * nn + zz * hv;
        }
    }
}

// ---------------------------------------------------------------------------
// Readout: out[g] += sigmoid(h@Wg.T+bg) * (h@Wp.T+bp), g = n2g[row].
// 32 rows/block; 128 out-cols = [64 proj | 64 gate] so pairs land in one thread.
// ---------------------------------------------------------------------------
__global__ __launch_bounds__(256) void k_readout(const float* __restrict__ h,
                                                 const int* __restrict__ n2g,
                                                 const float* __restrict__ Wp,
                                                 const float* __restrict__ bp,
                                                 const float* __restrict__ Wg,
                                                 const float* __restrict__ bg,
                                                 float* __restrict__ out) {
    __shared__ float hs[32][132];
    __shared__ float Ws[64][129];
    int tid = threadIdx.x;
    int row0 = blockIdx.x * 32;
    int rg = tid >> 5;
    int cg = tid & 31;
    float acc[4][4];
#pragma unroll
    for (int r = 0; r < 4; r++)
#pragma unroll
        for (int c = 0; c < 4; c++) acc[r][c] = 0.f;
#pragma unroll
    for (int p = 0; p < 4; p++) {
        int idx = p * 256 + tid;
        int r = idx >> 5;
        int c4 = idx & 31;
        *(float4*)&hs[r][c4 * 4] = *(const float4*)&h[(row0 + r) * HIDC + c4 * 4];
    }
    for (int kc = 0; kc < 128; kc += 64) {
        __syncthreads();
#pragma unroll
        for (int p = 0; p < 8; p++) {
            int idx = p * 256 + tid;
            int j = idx >> 4;
            int q = idx & 15;
            const float* Wsrc = (j < 64) ? Wp : Wg;
            float4 w = *(const float4*)&Wsrc[(j & 63) * HIDC + kc + q * 4];
            Ws[q * 4 + 0][j] = w.x;
            Ws[q * 4 + 1][j] = w.y;
            Ws[q * 4 + 2][j] = w.z;
            Ws[q * 4 + 3][j] = w.w;
        }
        __syncthreads();
#pragma unroll 8
        for (int k = 0; k < 64; k++) {
            float a[4], w[4];
#pragma unroll
            for (int r = 0; r < 4; r++) a[r] = hs[rg * 4 + r][kc + k];
#pragma unroll
            for (int c = 0; c < 4; c++) w[c] = Ws[k][cg + 32 * c];
#pragma unroll
            for (int r = 0; r < 4; r++)
#pragma unroll
                for (int c = 0; c < 4; c++) acc[r][c] += a[r] * w[c];
        }
    }
#pragma unroll
    for (int r = 0; r < 4; r++) {
        int row = row0 + rg * 4 + r;
        int g = n2g[row];
        float pv0 = acc[r][0] + bp[cg];
        float pv1 = acc[r][1] + bp[cg + 32];
        float gv0 = acc[r][2] + bg[cg];
        float gv1 = acc[r][3] + bg[cg + 32];
        atomicAdd(&out[g * EMBC + cg], pv0 / (1.f + expf(-gv0)));
        atomicAdd(&out[g * EMBC + cg + 32], pv1 / (1.f + expf(-gv1)));
    }
}

// ---------------------------------------------------------------------------
extern "C" void kernel_launch(void* const* d_in, const int* in_sizes, int n_in,
                              void* d_out, int out_size, void* d_ws, size_t ws_size,
                              hipStream_t stream) {
    const float* node_features = (const float*)d_in[0];
    const int*   edge_index    = (const int*)d_in[1];
    const int*   n2g           = (const int*)d_in[2];
    const float* W_msg         = (const float*)d_in[3];
    const float* b_msg         = (const float*)d_in[4];
    const float* W_ih          = (const float*)d_in[5];
    const float* W_hh          = (const float*)d_in[6];
    const float* b_ih          = (const float*)d_in[7];
    const float* b_hh          = (const float*)d_in[8];
    const float* W_proj        = (const float*)d_in[9];
    const float* b_proj        = (const float*)d_in[10];
    const float* W_gate        = (const float*)d_in[11];
    const float* b_gate        = (const float*)d_in[12];

    char* ws = (char*)d_ws;
    float* h    = (float*)(ws + 0);            // 51,200,000 B
    float* A    = (float*)(ws + 51200000);     // 51,200,000 B
    float* m    = (float*)(ws + 102400000);    // 51,200,000 B
    float* Wbig = (float*)(ws + 153600000);    // 524,288 B
    float* bbig = (float*)(ws + 154124288);    // 2,048 B
    int*   deg  = (int*)  (ws + 154126336);    // 1,200,000 B
    int*   csr  = (int*)  (ws + 155326336);    // 38,400,000 B  (end ~193.7 MB)

    float* out = (float*)d_out;

    hipMemsetAsync(out, 0, (size_t)N_GRAPHSC * EMBC * sizeof(float), stream);
    hipMemsetAsync(deg, 0, (size_t)3 * N_NODESC * sizeof(int), stream);
    hipMemcpyAsync(h, node_features, (size_t)N_NODESC * HIDC * sizeof(float),
                   hipMemcpyDeviceToDevice, stream);

    k_build_csr<<<dim3((3 * N_EDGESC + 255) / 256), dim3(256), 0, stream>>>(edge_index, deg, csr);
    k_build_wbig<<<dim3(512), dim3(256), 0, stream>>>(W_ih, W_hh, b_ih, b_hh, Wbig, bbig);

    for (int step = 0; step < 4; step++) {
        for (int t = 0; t < 3; t++) {
            k_aggregate<<<dim3(N_NODESC / 2), dim3(256), 0, stream>>>(h, deg, csr, A, t);
            k_msg_gemm<<<dim3(N_NODESC / 32), dim3(256), 0, stream>>>(
                A, W_msg + t * HIDC * HIDC, m, t > 0 ? 1 : 0);
        }
        k_gru<<<dim3(N_NODESC / 16), dim3(256), 0, stream>>>(m, h, deg, b_msg, Wbig, bbig);
    }
    k_readout<<<dim3(N_NODESC / 32), dim3(256), 0, stream>>>(h, n2g, W_proj, b_proj,
                                                             W_gate, b_gate, out);
}

// Round 2
// 1449.846 us; speedup vs baseline: 2.6748x; 2.6748x over previous
//
#include <hip/hip_runtime.h>
#include <hip/hip_bf16.h>
#include <math.h>

#define NN 100000
#define NNP 100096          // padded to 782*128
#define NE 300000
#define HID 128
#define EMB 64
#define NG 4096
#define DEG_CAP 32
#define XS 512              // X row stride in elements

typedef __bf16 bf16x8 __attribute__((ext_vector_type(8)));
typedef float  f32x16 __attribute__((ext_vector_type(16)));
typedef short  short8 __attribute__((ext_vector_type(8)));

__device__ __forceinline__ float bf2f(unsigned short u) {
    unsigned int x = ((unsigned int)u) << 16;
    return __builtin_bit_cast(float, x);
}
__device__ __forceinline__ unsigned short f2bf(float f) {
    unsigned int x = __builtin_bit_cast(unsigned int, f);
    unsigned int r = x + 0x7fff + ((x >> 16) & 1);
    return (unsigned short)(r >> 16);
}
__device__ __forceinline__ float sigm(float x) { return 1.f / (1.f + __expf(-x)); }

// ---------------------------------------------------------------------------
// h init: node_features f32 -> X[:,384:512] bf16
// ---------------------------------------------------------------------------
__global__ __launch_bounds__(256) void k_init(const float* __restrict__ nf,
                                              unsigned short* __restrict__ X) {
    int id = blockIdx.x * 256 + threadIdx.x;   // NN*HID
    int n = id >> 7, c = id & 127;
    X[(long)n * XS + 384 + c] = f2bf(nf[id]);
}

// ---------------------------------------------------------------------------
// CSR build (deg true counts; csr capped at DEG_CAP)
// ---------------------------------------------------------------------------
__global__ __launch_bounds__(256) void k_build_csr(const int* __restrict__ ei,
                                                   int* __restrict__ deg,
                                                   int* __restrict__ csr) {
    int id = blockIdx.x * 256 + threadIdx.x;
    if (id >= 3 * NE) return;
    int t = id / NE;
    int i = id - t * NE;
    int src = ei[(t * 2 + 0) * NE + i];
    int dst = ei[(t * 2 + 1) * NE + i];
    int p = atomicAdd(&deg[t * NN + dst], 1);
    if (p < DEG_CAP) csr[((long)t * NN + dst) * DEG_CAP + p] = src;
}

__global__ __launch_bounds__(256) void k_pack_deg(const int* __restrict__ deg,
                                                  int4* __restrict__ degp) {
    int n = blockIdx.x * 256 + threadIdx.x;
    if (n >= NNP) return;
    int4 v; v.x = 0; v.y = 0; v.z = 0; v.w = 0;
    if (n < NN) { v.x = deg[n]; v.y = deg[NN + n]; v.z = deg[2 * NN + n]; }
    degp[n] = v;
}

// ---------------------------------------------------------------------------
// Wnk[n][k] bf16, n = sec*128+c, K layout: k<384 -> A_cat (Wm @ Wih_sec^T),
// k>=384 -> h (Whh_sec). sec order: 0=r, 1=z, 2=In(i-only), 3=Hn(h-only).
// ---------------------------------------------------------------------------
__global__ __launch_bounds__(512) void k_build_w(const float* __restrict__ Wmsg,
                                                 const float* __restrict__ Wih,
                                                 const float* __restrict__ Whh,
                                                 unsigned short* __restrict__ Wnk) {
    int n = blockIdx.x;        // 0..511
    int k = threadIdx.x;       // 0..511
    int sec = n >> 7, c = n & 127;
    float v = 0.f;
    if (k < 384) {
        if (sec < 3) {
            int t = k >> 7, kk = k & 127;
            const float* wm = Wmsg + ((long)t * HID + kk) * HID;       // W_msg[t][kk][:]
            const float* wi = Wih + (long)(sec * HID + c) * HID;       // W_ih[sec*128+c][:]
            float s = 0.f;
            for (int j = 0; j < HID; j++) s += wm[j] * wi[j];
            v = s;
        }
    } else {
        int kk = k - 384;
        if (sec == 0)      v = Whh[(long)c * HID + kk];
        else if (sec == 1) v = Whh[(long)(HID + c) * HID + kk];
        else if (sec == 3) v = Whh[(long)(2 * HID + c) * HID + kk];
    }
    Wnk[(long)n * 512 + k] = f2bf(v);
}

__global__ __launch_bounds__(512) void k_build_bias(const float* __restrict__ bih,
                                                    const float* __restrict__ bhh,
                                                    const float* __restrict__ bmsg,
                                                    const float* __restrict__ Wih,
                                                    float* __restrict__ bbig,
                                                    float* __restrict__ Bdeg) {
    int n = threadIdx.x;       // 0..511
    int sec = n >> 7, c = n & 127;
    float b;
    if (sec == 0)      b = bih[c] + bhh[c];
    else if (sec == 1) b = bih[HID + c] + bhh[HID + c];
    else if (sec == 2) b = bih[2 * HID + c];
    else               b = bhh[2 * HID + c];
    bbig[n] = b;
    for (int t = 0; t < 3; t++) {
        float s = 0.f;
        if (sec < 3) {
            const float* wi = Wih + (long)(sec * HID + c) * HID;
            const float* bm = bmsg + t * HID;
            for (int j = 0; j < HID; j++) s += bm[j] * wi[j];
        }
        Bdeg[t * 512 + n] = s;
    }
}

// ---------------------------------------------------------------------------
// Aggregate all 3 edge types: X[n][t*128+c] = sum_src bf16(h[src][c])
// h read from X[:,384:512]. 2 nodes per 256-thread block.
// ---------------------------------------------------------------------------
__global__ __launch_bounds__(256) void k_agg(unsigned short* __restrict__ X,
                                             const int* __restrict__ deg,
                                             const int* __restrict__ csr) {
    int n = blockIdx.x * 2 + (threadIdx.x >> 7);
    int c = threadIdx.x & 127;
    unsigned short* Xn = X + (long)n * XS;
    for (int t = 0; t < 3; t++) {
        int d = deg[t * NN + n];
        if (d > DEG_CAP) d = DEG_CAP;
        const int* lst = csr + ((long)t * NN + n) * DEG_CAP;
        float s = 0.f;
        for (int k = 0; k < d; k++) {
            long src = lst[k];
            s += bf2f(X[src * XS + 384 + c]);
        }
        Xn[t * HID + c] = f2bf(s);
    }
}

// ---------------------------------------------------------------------------
// Fused GRU step: [A_cat|h] (K=512) x Wnk (N=512) MFMA GEMM + gates.
// BM=128, BN=512, BK=32, 8 waves, wave tile 64x128 (2x4 of 32x32).
// T14 reg-staged prefetch, XOR-swizzled LDS (16B unit ^= row&3).
// Epilogue: 8 x 16-row chunks through reused LDS, writes h bf16 into X.
// ---------------------------------------------------------------------------
__global__ __launch_bounds__(512, 2) void k_gru_mfma(
        unsigned short* __restrict__ X, const unsigned short* __restrict__ Wnk,
        const float* __restrict__ bbig, const float* __restrict__ Bdeg,
        const int4* __restrict__ degp) {
    __shared__ char lds[40960];
    char* Al = lds;                 // [128 rows][64 B]
    char* Bl = lds + 8192;          // [512 rows][64 B]

    const int tid = threadIdx.x;
    const int lane = tid & 63;
    const int wv = tid >> 6;
    const int wr = wv >> 2;         // 0..1
    const int wc = wv & 3;          // 0..3
    const int r31 = lane & 31;
    const int kg = lane >> 5;       // 0..1
    const int sw = lane & 3;
    const long row0 = (long)blockIdx.x * 128;

    f32x16 acc[2][4];
#pragma unroll
    for (int i = 0; i < 2; i++)
#pragma unroll
        for (int j = 0; j < 4; j++) acc[i][j] = (f32x16)(0.0f);

    // staging: thread covers (srow = tid>>2, unit su = tid&3); source swizzled
    const int srow = tid >> 2;
    const int su = tid & 3;
    const int swu = (su ^ (srow & 3)) * 16;
    const char* pA = (const char*)X + (row0 + srow) * 1024 + swu;
    const char* pB = (const char*)Wnk + (long)srow * 1024 + swu;

    float4 pa, pb0, pb1, pb2, pb3;
    pa  = *(const float4*)(pA);
    pb0 = *(const float4*)(pB);
    pb1 = *(const float4*)(pB + 131072);
    pb2 = *(const float4*)(pB + 262144);
    pb3 = *(const float4*)(pB + 393216);

    for (int it = 0; it < 16; it++) {
        __syncthreads();
        *(float4*)(Al + tid * 16)         = pa;
        *(float4*)(Bl + tid * 16)         = pb0;
        *(float4*)(Bl + 8192  + tid * 16) = pb1;
        *(float4*)(Bl + 16384 + tid * 16) = pb2;
        *(float4*)(Bl + 24576 + tid * 16) = pb3;
        if (it < 15) {
            long ko = (long)(it + 1) * 64;
            pa  = *(const float4*)(pA + ko);
            pb0 = *(const float4*)(pB + ko);
            pb1 = *(const float4*)(pB + 131072 + ko);
            pb2 = *(const float4*)(pB + 262144 + ko);
            pb3 = *(const float4*)(pB + 393216 + ko);
        }
        __syncthreads();

        short8 af[2][2], bfr[4][2];
#pragma unroll
        for (int rt = 0; rt < 2; rt++)
#pragma unroll
            for (int kb = 0; kb < 2; kb++)
                af[rt][kb] = *(const short8*)(Al + (wr * 64 + rt * 32 + r31) * 64 +
                                              (((2 * kb + kg) ^ sw) * 16));
#pragma unroll
        for (int ct = 0; ct < 4; ct++)
#pragma unroll
            for (int kb = 0; kb < 2; kb++)
                bfr[ct][kb] = *(const short8*)(Bl + (wc * 128 + ct * 32 + r31) * 64 +
                                               (((2 * kb + kg) ^ sw) * 16));
#pragma unroll
        for (int kb = 0; kb < 2; kb++)
#pragma unroll
            for (int rt = 0; rt < 2; rt++)
#pragma unroll
                for (int ct = 0; ct < 4; ct++)
                    acc[rt][ct] = __builtin_amdgcn_mfma_f32_32x32x16_bf16(
                        __builtin_bit_cast(bf16x8, af[rt][kb]),
                        __builtin_bit_cast(bf16x8, bfr[ct][kb]),
                        acc[rt][ct], 0, 0, 0);
    }

    // ---- epilogue: 8 chunks of 16 rows through LDS exchange ----
    float* EX = (float*)lds;        // [16][512] f32 = 32 KB
#pragma unroll
    for (int ch = 0; ch < 8; ch++) {
        __syncthreads();
        if (wr == (ch >> 2)) {
            const int rt = (ch >> 1) & 1;
            const int half = ch & 1;
#pragma unroll
            for (int ct = 0; ct < 4; ct++) {
                int n = wc * 128 + ct * 32 + r31;
#pragma unroll
                for (int q = 0; q < 8; q++) {
                    int row16 = (q & 3) + 8 * ((q >> 2) & 1) + 4 * kg;
                    EX[row16 * 512 + n] = acc[rt][ct][half * 8 + q];
                }
            }
        }
        __syncthreads();
        {
            int row16 = tid >> 5;
            int c0 = (tid & 31) << 2;
            long grow = row0 + ch * 16 + row16;
            int4 dg = degp[grow];
            float dgx = (float)dg.x, dgy = (float)dg.y, dgz = (float)dg.z;
            const float* ex = EX + row16 * 512;
            float4 vr = *(const float4*)(ex + c0);
            float4 vz = *(const float4*)(ex + 128 + c0);
            float4 vn = *(const float4*)(ex + 256 + c0);
            float4 vh = *(const float4*)(ex + 384 + c0);
            float4 br = *(const float4*)(bbig + c0);
            float4 bz = *(const float4*)(bbig + 128 + c0);
            float4 bn = *(const float4*)(bbig + 256 + c0);
            float4 bh = *(const float4*)(bbig + 384 + c0);
            float4 d00 = *(const float4*)(Bdeg + c0);
            float4 d01 = *(const float4*)(Bdeg + 128 + c0);
            float4 d02 = *(const float4*)(Bdeg + 256 + c0);
            float4 d10 = *(const float4*)(Bdeg + 512 + c0);
            float4 d11 = *(const float4*)(Bdeg + 512 + 128 + c0);
            float4 d12 = *(const float4*)(Bdeg + 512 + 256 + c0);
            float4 d20 = *(const float4*)(Bdeg + 1024 + c0);
            float4 d21 = *(const float4*)(Bdeg + 1024 + 128 + c0);
            float4 d22 = *(const float4*)(Bdeg + 1024 + 256 + c0);
            ushort4 ho = *(const ushort4*)(X + grow * XS + 384 + c0);

            float aR[4] = {vr.x, vr.y, vr.z, vr.w};
            float aZ[4] = {vz.x, vz.y, vz.z, vz.w};
            float aN[4] = {vn.x, vn.y, vn.z, vn.w};
            float aH[4] = {vh.x, vh.y, vh.z, vh.w};
            float bR[4] = {br.x, br.y, br.z, br.w};
            float bZ[4] = {bz.x, bz.y, bz.z, bz.w};
            float bN[4] = {bn.x, bn.y, bn.z, bn.w};
            float bH[4] = {bh.x, bh.y, bh.z, bh.w};
            float e00[4] = {d00.x, d00.y, d00.z, d00.w};
            float e01[4] = {d01.x, d01.y, d01.z, d01.w};
            float e02[4] = {d02.x, d02.y, d02.z, d02.w};
            float e10[4] = {d10.x, d10.y, d10.z, d10.w};
            float e11[4] = {d11.x, d11.y, d11.z, d11.w};
            float e12[4] = {d12.x, d12.y, d12.z, d12.w};
            float e20[4] = {d20.x, d20.y, d20.z, d20.w};
            float e21[4] = {d21.x, d21.y, d21.z, d21.w};
            float e22[4] = {d22.x, d22.y, d22.z, d22.w};
            unsigned short hold[4] = {ho.x, ho.y, ho.z, ho.w};

            ushort4 outp;
            unsigned short* op = (unsigned short*)&outp;
#pragma unroll
            for (int cc = 0; cc < 4; cc++) {
                float Sr = aR[cc] + bR[cc] + dgx * e00[cc] + dgy * e10[cc] + dgz * e20[cc];
                float Sz = aZ[cc] + bZ[cc] + dgx * e01[cc] + dgy * e11[cc] + dgz * e21[cc];
                float In = aN[cc] + bN[cc] + dgx * e02[cc] + dgy * e12[cc] + dgz * e22[cc];
                float Hn = aH[cc] + bH[cc];
                float rr = sigm(Sr);
                float zz = sigm(Sz);
                float tt = In + rr * Hn;
                float e2 = __expf(2.f * tt);
                float nn = 1.f - 2.f / (e2 + 1.f);
                float hv = (1.f - zz) * nn + zz * bf2f(hold[cc]);
                op[cc] = f2bf(hv);
            }
            *(ushort4*)(X + grow * XS + 384 + c0) = outp;
        }
    }
}

// ---------------------------------------------------------------------------
// Readout: out[g] += sigmoid(h@Wg.T+bg) * (h@Wp.T+bp). h from X bf16.
// 32 rows/block, fp32 vector GEMM (tiny FLOPs), block-local rows -> atomics.
// ---------------------------------------------------------------------------
__global__ __launch_bounds__(256) void k_readout(const unsigned short* __restrict__ X,
                                                 const int* __restrict__ n2g,
                                                 const float* __restrict__ Wp,
                                                 const float* __restrict__ bp,
                                                 const float* __restrict__ Wg,
                                                 const float* __restrict__ bg,
                                                 float* __restrict__ out) {
    __shared__ float hs[32][132];
    __shared__ float Ws[64][129];
    int tid = threadIdx.x;
    long row0 = (long)blockIdx.x * 32;
    int rg = tid >> 5, cg = tid & 31;
    float acc[4][4];
#pragma unroll
    for (int r = 0; r < 4; r++)
#pragma unroll
        for (int c = 0; c < 4; c++) acc[r][c] = 0.f;

#pragma unroll
    for (int p = 0; p < 2; p++) {
        int e = p * 256 + tid;
        int r = e >> 4, c8 = e & 15;
        short8 v = *(const short8*)(X + (row0 + r) * XS + 384 + c8 * 8);
#pragma unroll
        for (int j = 0; j < 8; j++) hs[r][c8 * 8 + j] = bf2f((unsigned short)v[j]);
    }
    for (int kc = 0; kc < 128; kc += 64) {
        __syncthreads();
#pragma unroll
        for (int p = 0; p < 8; p++) {
            int idx = p * 256 + tid;
            int j = idx >> 4, q = idx & 15;
            const float* Wsrc = (j < 64) ? Wp : Wg;
            float4 w = *(const float4*)&Wsrc[(j & 63) * HID + kc + q * 4];
            Ws[q * 4 + 0][j] = w.x;
            Ws[q * 4 + 1][j] = w.y;
            Ws[q * 4 + 2][j] = w.z;
            Ws[q * 4 + 3][j] = w.w;
        }
        __syncthreads();
#pragma unroll 8
        for (int k = 0; k < 64; k++) {
            float a[4], w[4];
#pragma unroll
            for (int r = 0; r < 4; r++) a[r] = hs[rg * 4 + r][kc + k];
#pragma unroll
            for (int c = 0; c < 4; c++) w[c] = Ws[k][cg + 32 * c];
#pragma unroll
            for (int r = 0; r < 4; r++)
#pragma unroll
                for (int c = 0; c < 4; c++) acc[r][c] += a[r] * w[c];
        }
    }
#pragma unroll
    for (int r = 0; r < 4; r++) {
        long row = row0 + rg * 4 + r;
        if (row < NN) {
            int g = n2g[row];
            float pv0 = acc[r][0] + bp[cg];
            float pv1 = acc[r][1] + bp[cg + 32];
            float gv0 = acc[r][2] + bg[cg];
            float gv1 = acc[r][3] + bg[cg + 32];
            atomicAdd(&out[g * EMB + cg],      pv0 * sigm(gv0));
            atomicAdd(&out[g * EMB + cg + 32], pv1 * sigm(gv1));
        }
    }
}

// ---------------------------------------------------------------------------
extern "C" void kernel_launch(void* const* d_in, const int* in_sizes, int n_in,
                              void* d_out, int out_size, void* d_ws, size_t ws_size,
                              hipStream_t stream) {
    const float* node_features = (const float*)d_in[0];
    const int*   edge_index    = (const int*)d_in[1];
    const int*   n2g           = (const int*)d_in[2];
    const float* W_msg         = (const float*)d_in[3];
    const float* b_msg         = (const float*)d_in[4];
    const float* W_ih          = (const float*)d_in[5];
    const float* W_hh          = (const float*)d_in[6];
    const float* b_ih          = (const float*)d_in[7];
    const float* b_hh          = (const float*)d_in[8];
    const float* W_proj        = (const float*)d_in[9];
    const float* b_proj        = (const float*)d_in[10];
    const float* W_gate        = (const float*)d_in[11];
    const float* b_gate        = (const float*)d_in[12];

    char* ws = (char*)d_ws;
    unsigned short* X    = (unsigned short*)(ws);                 // 102,498,304 B
    unsigned short* Wnk  = (unsigned short*)(ws + 102498304);     //    524,288 B
    float*          bbig = (float*)         (ws + 103022592);     //      2,048 B
    float*          Bdeg = (float*)         (ws + 103024640);     //      6,144 B
    int4*           degp = (int4*)          (ws + 103030784);     //  1,601,536 B
    int*            deg  = (int*)           (ws + 104632320);     //  1,200,000 B
    int*            csr  = (int*)           (ws + 105832320);     // 38,400,000 B -> 144,232,320

    float* out = (float*)d_out;

    hipMemsetAsync(out, 0, (size_t)NG * EMB * sizeof(float), stream);
    hipMemsetAsync(deg, 0, (size_t)3 * NN * sizeof(int), stream);

    k_init<<<dim3((NN * HID) / 256), dim3(256), 0, stream>>>(node_features, X);
    k_build_csr<<<dim3((3 * NE + 255) / 256), dim3(256), 0, stream>>>(edge_index, deg, csr);
    k_pack_deg<<<dim3(NNP / 256), dim3(256), 0, stream>>>(deg, degp);
    k_build_w<<<dim3(512), dim3(512), 0, stream>>>(W_msg, W_ih, W_hh, Wnk);
    k_build_bias<<<dim3(1), dim3(512), 0, stream>>>(b_ih, b_hh, b_msg, W_ih, bbig, Bdeg);

    for (int step = 0; step < 4; step++) {
        k_agg<<<dim3(NN / 2), dim3(256), 0, stream>>>(X, deg, csr);
        k_gru_mfma<<<dim3(NNP / 128), dim3(512), 0, stream>>>(X, Wnk, bbig, Bdeg, degp);
    }
    k_readout<<<dim3(NN / 32), dim3(256), 0, stream>>>(X, n2g, W_proj, b_proj,
                                                       W_gate, b_gate, out);
}

// Round 3
// 991.126 us; speedup vs baseline: 3.9128x; 1.4628x over previous
//
#include <hip/hip_runtime.h>
#include <hip/hip_bf16.h>
#include <math.h>

#define NN 100000
#define NNP 100096          // padded to 782*128
#define NE 300000
#define HID 128
#define EMB 64
#define NG 4096
#define DEG_CAP 32
#define XS 512              // X row stride in elements

typedef __bf16 bf16x8 __attribute__((ext_vector_type(8)));
typedef float  f32x16 __attribute__((ext_vector_type(16)));
typedef short  short8 __attribute__((ext_vector_type(8)));

__device__ __forceinline__ float bf2f(unsigned short u) {
    unsigned int x = ((unsigned int)u) << 16;
    return __builtin_bit_cast(float, x);
}
__device__ __forceinline__ unsigned short f2bf(float f) {
    unsigned int x = __builtin_bit_cast(unsigned int, f);
    unsigned int r = x + 0x7fff + ((x >> 16) & 1);
    return (unsigned short)(r >> 16);
}
__device__ __forceinline__ float sigm(float x) { return 1.f / (1.f + __expf(-x)); }

// ---------------------------------------------------------------------------
// h init: node_features f32 -> X[:,384:512] bf16
// ---------------------------------------------------------------------------
__global__ __launch_bounds__(256) void k_init(const float* __restrict__ nf,
                                              unsigned short* __restrict__ X) {
    int id = blockIdx.x * 256 + threadIdx.x;   // NN*HID
    int n = id >> 7, c = id & 127;
    X[(long)n * XS + 384 + c] = f2bf(nf[id]);
}

// ---------------------------------------------------------------------------
// CSR build (deg true counts; csr capped at DEG_CAP)
// ---------------------------------------------------------------------------
__global__ __launch_bounds__(256) void k_build_csr(const int* __restrict__ ei,
                                                   int* __restrict__ deg,
                                                   int* __restrict__ csr) {
    int id = blockIdx.x * 256 + threadIdx.x;
    if (id >= 3 * NE) return;
    int t = id / NE;
    int i = id - t * NE;
    int src = ei[(t * 2 + 0) * NE + i];
    int dst = ei[(t * 2 + 1) * NE + i];
    int p = atomicAdd(&deg[t * NN + dst], 1);
    if (p < DEG_CAP) csr[((long)t * NN + dst) * DEG_CAP + p] = src;
}

__global__ __launch_bounds__(256) void k_pack_deg(const int* __restrict__ deg,
                                                  int4* __restrict__ degp) {
    int n = blockIdx.x * 256 + threadIdx.x;
    if (n >= NNP) return;
    int4 v; v.x = 0; v.y = 0; v.z = 0; v.w = 0;
    if (n < NN) { v.x = deg[n]; v.y = deg[NN + n]; v.z = deg[2 * NN + n]; }
    degp[n] = v;
}

// ---------------------------------------------------------------------------
// Wnk[n][k] bf16, n = sec*128+c, K layout: k<384 -> A_cat (Wm @ Wih_sec^T),
// k>=384 -> h (Whh_sec). sec order: 0=r, 1=z, 2=In(i-only), 3=Hn(h-only).
// ---------------------------------------------------------------------------
__global__ __launch_bounds__(512) void k_build_w(const float* __restrict__ Wmsg,
                                                 const float* __restrict__ Wih,
                                                 const float* __restrict__ Whh,
                                                 unsigned short* __restrict__ Wnk) {
    int n = blockIdx.x;        // 0..511
    int k = threadIdx.x;       // 0..511
    int sec = n >> 7, c = n & 127;
    float v = 0.f;
    if (k < 384) {
        if (sec < 3) {
            int t = k >> 7, kk = k & 127;
            const float* wm = Wmsg + ((long)t * HID + kk) * HID;       // W_msg[t][kk][:]
            const float* wi = Wih + (long)(sec * HID + c) * HID;       // W_ih[sec*128+c][:]
            float s = 0.f;
            for (int j = 0; j < HID; j++) s += wm[j] * wi[j];
            v = s;
        }
    } else {
        int kk = k - 384;
        if (sec == 0)      v = Whh[(long)c * HID + kk];
        else if (sec == 1) v = Whh[(long)(HID + c) * HID + kk];
        else if (sec == 3) v = Whh[(long)(2 * HID + c) * HID + kk];
    }
    Wnk[(long)n * 512 + k] = f2bf(v);
}

__global__ __launch_bounds__(512) void k_build_bias(const float* __restrict__ bih,
                                                    const float* __restrict__ bhh,
                                                    const float* __restrict__ bmsg,
                                                    const float* __restrict__ Wih,
                                                    float* __restrict__ bbig,
                                                    float* __restrict__ Bdeg) {
    int n = threadIdx.x;       // 0..511
    int sec = n >> 7, c = n & 127;
    float b;
    if (sec == 0)      b = bih[c] + bhh[c];
    else if (sec == 1) b = bih[HID + c] + bhh[HID + c];
    else if (sec == 2) b = bih[2 * HID + c];
    else               b = bhh[2 * HID + c];
    bbig[n] = b;
    for (int t = 0; t < 3; t++) {
        float s = 0.f;
        if (sec < 3) {
            const float* wi = Wih + (long)(sec * HID + c) * HID;
            const float* bm = bmsg + t * HID;
            for (int j = 0; j < HID; j++) s += bm[j] * wi[j];
        }
        Bdeg[t * 512 + n] = s;
    }
}

// ---------------------------------------------------------------------------
// Aggregate, MLP-optimized: one WAVE per node. Lane = (g = l>>4 neighbor
// group) x (c16 = l&15 16B chunk). Each short8 load covers 4 neighbors in
// parallel; csr index rows hoisted up front; cross-group reduce via shfl_xor.
// ---------------------------------------------------------------------------
__global__ __launch_bounds__(256) void k_agg(unsigned short* __restrict__ X,
                                             const int* __restrict__ deg,
                                             const int* __restrict__ csr) {
    const int lane = threadIdx.x & 63;
    const long n = (long)blockIdx.x * 4 + (threadIdx.x >> 6);
    const int g = lane >> 4;
    const int c16 = lane & 15;
    const int l31 = lane & 31;

    int d[3], il[3];
#pragma unroll
    for (int t = 0; t < 3; t++) {
        int dt = deg[t * NN + n];
        d[t] = dt > DEG_CAP ? DEG_CAP : dt;
        il[t] = csr[((long)t * NN + n) * DEG_CAP + l31];
    }
#pragma unroll
    for (int t = 0; t < 3; t++) {
        float acc[8] = {0.f, 0.f, 0.f, 0.f, 0.f, 0.f, 0.f, 0.f};
        int rounds = (d[t] + 3) >> 2;
        for (int r = 0; r < rounds; r++) {
            int j = r * 4 + g;
            int idx = __shfl(il[t], j & 31);
            if (j < d[t]) {
                short8 v = *(const short8*)(X + (long)idx * XS + 384 + c16 * 8);
#pragma unroll
                for (int q = 0; q < 8; q++) acc[q] += bf2f((unsigned short)v[q]);
            }
        }
#pragma unroll
        for (int q = 0; q < 8; q++) {
            acc[q] += __shfl_xor(acc[q], 16);
            acc[q] += __shfl_xor(acc[q], 32);
        }
        if (g == 0) {
            short8 o;
#pragma unroll
            for (int q = 0; q < 8; q++) o[q] = (short)f2bf(acc[q]);
            *(short8*)(X + n * XS + t * HID + c16 * 8) = o;
        }
    }
}

// ---------------------------------------------------------------------------
// Fused GRU step: [A_cat|h] (K=512) x Wnk (N=512) MFMA GEMM + gates.
// BM=128, BN=512, BK=32, 8 waves, wave tile 64x128 (2x4 of 32x32).
// T14 reg-staged prefetch, XOR-swizzled LDS (16B unit ^= row&3).
// Epilogue: 8 x 16-row chunks through reused LDS, writes h bf16 into X.
// ---------------------------------------------------------------------------
__global__ __launch_bounds__(512, 2) void k_gru_mfma(
        unsigned short* __restrict__ X, const unsigned short* __restrict__ Wnk,
        const float* __restrict__ bbig, const float* __restrict__ Bdeg,
        const int4* __restrict__ degp) {
    __shared__ char lds[40960];
    char* Al = lds;                 // [128 rows][64 B]
    char* Bl = lds + 8192;          // [512 rows][64 B]

    const int tid = threadIdx.x;
    const int lane = tid & 63;
    const int wv = tid >> 6;
    const int wr = wv >> 2;         // 0..1
    const int wc = wv & 3;          // 0..3
    const int r31 = lane & 31;
    const int kg = lane >> 5;       // 0..1
    const int sw = lane & 3;
    const long row0 = (long)blockIdx.x * 128;

    f32x16 acc[2][4];
#pragma unroll
    for (int i = 0; i < 2; i++)
#pragma unroll
        for (int j = 0; j < 4; j++) acc[i][j] = (f32x16)(0.0f);

    // staging: thread covers (srow = tid>>2, unit su = tid&3); source swizzled
    const int srow = tid >> 2;
    const int su = tid & 3;
    const int swu = (su ^ (srow & 3)) * 16;
    const char* pA = (const char*)X + (row0 + srow) * 1024 + swu;
    const char* pB = (const char*)Wnk + (long)srow * 1024 + swu;

    float4 pa, pb0, pb1, pb2, pb3;
    pa  = *(const float4*)(pA);
    pb0 = *(const float4*)(pB);
    pb1 = *(const float4*)(pB + 131072);
    pb2 = *(const float4*)(pB + 262144);
    pb3 = *(const float4*)(pB + 393216);

    for (int it = 0; it < 16; it++) {
        __syncthreads();
        *(float4*)(Al + tid * 16)         = pa;
        *(float4*)(Bl + tid * 16)         = pb0;
        *(float4*)(Bl + 8192  + tid * 16) = pb1;
        *(float4*)(Bl + 16384 + tid * 16) = pb2;
        *(float4*)(Bl + 24576 + tid * 16) = pb3;
        if (it < 15) {
            long ko = (long)(it + 1) * 64;
            pa  = *(const float4*)(pA + ko);
            pb0 = *(const float4*)(pB + ko);
            pb1 = *(const float4*)(pB + 131072 + ko);
            pb2 = *(const float4*)(pB + 262144 + ko);
            pb3 = *(const float4*)(pB + 393216 + ko);
        }
        __syncthreads();

        short8 af[2][2], bfr[4][2];
#pragma unroll
        for (int rt = 0; rt < 2; rt++)
#pragma unroll
            for (int kb = 0; kb < 2; kb++)
                af[rt][kb] = *(const short8*)(Al + (wr * 64 + rt * 32 + r31) * 64 +
                                              (((2 * kb + kg) ^ sw) * 16));
#pragma unroll
        for (int ct = 0; ct < 4; ct++)
#pragma unroll
            for (int kb = 0; kb < 2; kb++)
                bfr[ct][kb] = *(const short8*)(Bl + (wc * 128 + ct * 32 + r31) * 64 +
                                               (((2 * kb + kg) ^ sw) * 16));
#pragma unroll
        for (int kb = 0; kb < 2; kb++)
#pragma unroll
            for (int rt = 0; rt < 2; rt++)
#pragma unroll
                for (int ct = 0; ct < 4; ct++)
                    acc[rt][ct] = __builtin_amdgcn_mfma_f32_32x32x16_bf16(
                        __builtin_bit_cast(bf16x8, af[rt][kb]),
                        __builtin_bit_cast(bf16x8, bfr[ct][kb]),
                        acc[rt][ct], 0, 0, 0);
    }

    // ---- epilogue: 8 chunks of 16 rows through LDS exchange ----
    float* EX = (float*)lds;        // [16][512] f32 = 32 KB
#pragma unroll
    for (int ch = 0; ch < 8; ch++) {
        __syncthreads();
        if (wr == (ch >> 2)) {
            const int rt = (ch >> 1) & 1;
            const int half = ch & 1;
#pragma unroll
            for (int ct = 0; ct < 4; ct++) {
                int n = wc * 128 + ct * 32 + r31;
#pragma unroll
                for (int q = 0; q < 8; q++) {
                    int row16 = (q & 3) + 8 * ((q >> 2) & 1) + 4 * kg;
                    EX[row16 * 512 + n] = acc[rt][ct][half * 8 + q];
                }
            }
        }
        __syncthreads();
        {
            int row16 = tid >> 5;
            int c0 = (tid & 31) << 2;
            long grow = row0 + ch * 16 + row16;
            int4 dg = degp[grow];
            float dgx = (float)dg.x, dgy = (float)dg.y, dgz = (float)dg.z;
            const float* ex = EX + row16 * 512;
            float4 vr = *(const float4*)(ex + c0);
            float4 vz = *(const float4*)(ex + 128 + c0);
            float4 vn = *(const float4*)(ex + 256 + c0);
            float4 vh = *(const float4*)(ex + 384 + c0);
            float4 br = *(const float4*)(bbig + c0);
            float4 bz = *(const float4*)(bbig + 128 + c0);
            float4 bn = *(const float4*)(bbig + 256 + c0);
            float4 bh = *(const float4*)(bbig + 384 + c0);
            float4 d00 = *(const float4*)(Bdeg + c0);
            float4 d01 = *(const float4*)(Bdeg + 128 + c0);
            float4 d02 = *(const float4*)(Bdeg + 256 + c0);
            float4 d10 = *(const float4*)(Bdeg + 512 + c0);
            float4 d11 = *(const float4*)(Bdeg + 512 + 128 + c0);
            float4 d12 = *(const float4*)(Bdeg + 512 + 256 + c0);
            float4 d20 = *(const float4*)(Bdeg + 1024 + c0);
            float4 d21 = *(const float4*)(Bdeg + 1024 + 128 + c0);
            float4 d22 = *(const float4*)(Bdeg + 1024 + 256 + c0);
            ushort4 ho = *(const ushort4*)(X + grow * XS + 384 + c0);

            float aR[4] = {vr.x, vr.y, vr.z, vr.w};
            float aZ[4] = {vz.x, vz.y, vz.z, vz.w};
            float aN[4] = {vn.x, vn.y, vn.z, vn.w};
            float aH[4] = {vh.x, vh.y, vh.z, vh.w};
            float bR[4] = {br.x, br.y, br.z, br.w};
            float bZ[4] = {bz.x, bz.y, bz.z, bz.w};
            float bN[4] = {bn.x, bn.y, bn.z, bn.w};
            float bH[4] = {bh.x, bh.y, bh.z, bh.w};
            float e00[4] = {d00.x, d00.y, d00.z, d00.w};
            float e01[4] = {d01.x, d01.y, d01.z, d01.w};
            float e02[4] = {d02.x, d02.y, d02.z, d02.w};
            float e10[4] = {d10.x, d10.y, d10.z, d10.w};
            float e11[4] = {d11.x, d11.y, d11.z, d11.w};
            float e12[4] = {d12.x, d12.y, d12.z, d12.w};
            float e20[4] = {d20.x, d20.y, d20.z, d20.w};
            float e21[4] = {d21.x, d21.y, d21.z, d21.w};
            float e22[4] = {d22.x, d22.y, d22.z, d22.w};
            unsigned short hold[4] = {ho.x, ho.y, ho.z, ho.w};

            ushort4 outp;
            unsigned short* op = (unsigned short*)&outp;
#pragma unroll
            for (int cc = 0; cc < 4; cc++) {
                float Sr = aR[cc] + bR[cc] + dgx * e00[cc] + dgy * e10[cc] + dgz * e20[cc];
                float Sz = aZ[cc] + bZ[cc] + dgx * e01[cc] + dgy * e11[cc] + dgz * e21[cc];
                float In = aN[cc] + bN[cc] + dgx * e02[cc] + dgy * e12[cc] + dgz * e22[cc];
                float Hn = aH[cc] + bH[cc];
                float rr = sigm(Sr);
                float zz = sigm(Sz);
                float tt = In + rr * Hn;
                float e2 = __expf(2.f * tt);
                float nn = 1.f - 2.f / (e2 + 1.f);
                float hv = (1.f - zz) * nn + zz * bf2f(hold[cc]);
                op[cc] = f2bf(hv);
            }
            *(ushort4*)(X + grow * XS + 384 + c0) = outp;
        }
    }
}

// ---------------------------------------------------------------------------
// Readout: out[g] += sigmoid(h@Wg.T+bg) * (h@Wp.T+bp). h from X bf16.
// 32 rows/block, fp32 vector GEMM (tiny FLOPs), block-local rows -> atomics.
// ---------------------------------------------------------------------------
__global__ __launch_bounds__(256) void k_readout(const unsigned short* __restrict__ X,
                                                 const int* __restrict__ n2g,
                                                 const float* __restrict__ Wp,
                                                 const float* __restrict__ bp,
                                                 const float* __restrict__ Wg,
                                                 const float* __restrict__ bg,
                                                 float* __restrict__ out) {
    __shared__ float hs[32][132];
    __shared__ float Ws[64][129];
    int tid = threadIdx.x;
    long row0 = (long)blockIdx.x * 32;
    int rg = tid >> 5, cg = tid & 31;
    float acc[4][4];
#pragma unroll
    for (int r = 0; r < 4; r++)
#pragma unroll
        for (int c = 0; c < 4; c++) acc[r][c] = 0.f;

#pragma unroll
    for (int p = 0; p < 2; p++) {
        int e = p * 256 + tid;
        int r = e >> 4, c8 = e & 15;
        short8 v = *(const short8*)(X + (row0 + r) * XS + 384 + c8 * 8);
#pragma unroll
        for (int j = 0; j < 8; j++) hs[r][c8 * 8 + j] = bf2f((unsigned short)v[j]);
    }
    for (int kc = 0; kc < 128; kc += 64) {
        __syncthreads();
#pragma unroll
        for (int p = 0; p < 8; p++) {
            int idx = p * 256 + tid;
            int j = idx >> 4, q = idx & 15;
            const float* Wsrc = (j < 64) ? Wp : Wg;
            float4 w = *(const float4*)&Wsrc[(j & 63) * HID + kc + q * 4];
            Ws[q * 4 + 0][j] = w.x;
            Ws[q * 4 + 1][j] = w.y;
            Ws[q * 4 + 2][j] = w.z;
            Ws[q * 4 + 3][j] = w.w;
        }
        __syncthreads();
#pragma unroll 8
        for (int k = 0; k < 64; k++) {
            float a[4], w[4];
#pragma unroll
            for (int r = 0; r < 4; r++) a[r] = hs[rg * 4 + r][kc + k];
#pragma unroll
            for (int c = 0; c < 4; c++) w[c] = Ws[k][cg + 32 * c];
#pragma unroll
            for (int r = 0; r < 4; r++)
#pragma unroll
                for (int c = 0; c < 4; c++) acc[r][c] += a[r] * w[c];
        }
    }
#pragma unroll
    for (int r = 0; r < 4; r++) {
        long row = row0 + rg * 4 + r;
        if (row < NN) {
            int g = n2g[row];
            float pv0 = acc[r][0] + bp[cg];
            float pv1 = acc[r][1] + bp[cg + 32];
            float gv0 = acc[r][2] + bg[cg];
            float gv1 = acc[r][3] + bg[cg + 32];
            atomicAdd(&out[g * EMB + cg],      pv0 * sigm(gv0));
            atomicAdd(&out[g * EMB + cg + 32], pv1 * sigm(gv1));
        }
    }
}

// ---------------------------------------------------------------------------
extern "C" void kernel_launch(void* const* d_in, const int* in_sizes, int n_in,
                              void* d_out, int out_size, void* d_ws, size_t ws_size,
                              hipStream_t stream) {
    const float* node_features = (const float*)d_in[0];
    const int*   edge_index    = (const int*)d_in[1];
    const int*   n2g           = (const int*)d_in[2];
    const float* W_msg         = (const float*)d_in[3];
    const float* b_msg         = (const float*)d_in[4];
    const float* W_ih          = (const float*)d_in[5];
    const float* W_hh          = (const float*)d_in[6];
    const float* b_ih          = (const float*)d_in[7];
    const float* b_hh          = (const float*)d_in[8];
    const float* W_proj        = (const float*)d_in[9];
    const float* b_proj        = (const float*)d_in[10];
    const float* W_gate        = (const float*)d_in[11];
    const float* b_gate        = (const float*)d_in[12];

    char* ws = (char*)d_ws;
    unsigned short* X    = (unsigned short*)(ws);                 // 102,498,304 B
    unsigned short* Wnk  = (unsigned short*)(ws + 102498304);     //    524,288 B
    float*          bbig = (float*)         (ws + 103022592);     //      2,048 B
    float*          Bdeg = (float*)         (ws + 103024640);     //      6,144 B
    int4*           degp = (int4*)          (ws + 103030784);     //  1,601,536 B
    int*            deg  = (int*)           (ws + 104632320);     //  1,200,000 B
    int*            csr  = (int*)           (ws + 105832320);     // 38,400,000 B -> 144,232,320

    float* out = (float*)d_out;

    hipMemsetAsync(out, 0, (size_t)NG * EMB * sizeof(float), stream);
    hipMemsetAsync(deg, 0, (size_t)3 * NN * sizeof(int), stream);

    k_init<<<dim3((NN * HID) / 256), dim3(256), 0, stream>>>(node_features, X);
    k_build_csr<<<dim3((3 * NE + 255) / 256), dim3(256), 0, stream>>>(edge_index, deg, csr);
    k_pack_deg<<<dim3(NNP / 256), dim3(256), 0, stream>>>(deg, degp);
    k_build_w<<<dim3(512), dim3(512), 0, stream>>>(W_msg, W_ih, W_hh, Wnk);
    k_build_bias<<<dim3(1), dim3(512), 0, stream>>>(b_ih, b_hh, b_msg, W_ih, bbig, Bdeg);

    for (int step = 0; step < 4; step++) {
        k_agg<<<dim3(NN / 4), dim3(256), 0, stream>>>(X, deg, csr);
        k_gru_mfma<<<dim3(NNP / 128), dim3(512), 0, stream>>>(X, Wnk, bbig, Bdeg, degp);
    }
    k_readout<<<dim3(NN / 32), dim3(256), 0, stream>>>(X, n2g, W_proj, b_proj,
                                                       W_gate, b_gate, out);
}

// Round 4
// 940.615 us; speedup vs baseline: 4.1229x; 1.0537x over previous
//
#include <hip/hip_runtime.h>
#include <hip/hip_bf16.h>
#include <math.h>

#define NN 100000
#define NNP 100096          // padded to 782*128
#define NE 300000
#define HID 128
#define EMB 64
#define NG 4096
#define DEG_CAP 32
#define XS 512              // X row stride in elements

typedef __bf16 bf16x8 __attribute__((ext_vector_type(8)));
typedef float  f32x16 __attribute__((ext_vector_type(16)));
typedef short  short8 __attribute__((ext_vector_type(8)));

__device__ __forceinline__ float bf2f(unsigned short u) {
    unsigned int x = ((unsigned int)u) << 16;
    return __builtin_bit_cast(float, x);
}
__device__ __forceinline__ unsigned short f2bf(float f) {
    unsigned int x = __builtin_bit_cast(unsigned int, f);
    unsigned int r = x + 0x7fff + ((x >> 16) & 1);
    return (unsigned short)(r >> 16);
}
__device__ __forceinline__ float sigm(float x) { return 1.f / (1.f + __expf(-x)); }

// ---------------------------------------------------------------------------
// h init: node_features f32 -> X[:,384:512] bf16
// ---------------------------------------------------------------------------
__global__ __launch_bounds__(256) void k_init(const float* __restrict__ nf,
                                              unsigned short* __restrict__ X) {
    int id = blockIdx.x * 256 + threadIdx.x;   // NN*HID
    int n = id >> 7, c = id & 127;
    X[(long)n * XS + 384 + c] = f2bf(nf[id]);
}

// ---------------------------------------------------------------------------
// CSR build (deg true counts; csr capped at DEG_CAP)
// ---------------------------------------------------------------------------
__global__ __launch_bounds__(256) void k_build_csr(const int* __restrict__ ei,
                                                   int* __restrict__ deg,
                                                   int* __restrict__ csr) {
    int id = blockIdx.x * 256 + threadIdx.x;
    if (id >= 3 * NE) return;
    int t = id / NE;
    int i = id - t * NE;
    int src = ei[(t * 2 + 0) * NE + i];
    int dst = ei[(t * 2 + 1) * NE + i];
    int p = atomicAdd(&deg[t * NN + dst], 1);
    if (p < DEG_CAP) csr[((long)t * NN + dst) * DEG_CAP + p] = src;
}

__global__ __launch_bounds__(256) void k_pack_deg(const int* __restrict__ deg,
                                                  int4* __restrict__ degp) {
    int n = blockIdx.x * 256 + threadIdx.x;
    if (n >= NNP) return;
    int4 v; v.x = 0; v.y = 0; v.z = 0; v.w = 0;
    if (n < NN) { v.x = deg[n]; v.y = deg[NN + n]; v.z = deg[2 * NN + n]; }
    degp[n] = v;
}

// ---------------------------------------------------------------------------
// Wnk[n][k] bf16, n = sec*128+c, K layout: k<384 -> A_cat (Wm @ Wih_sec^T),
// k>=384 -> h (Whh_sec). sec order: 0=r, 1=z, 2=In(i-only), 3=Hn(h-only).
// ---------------------------------------------------------------------------
__global__ __launch_bounds__(512) void k_build_w(const float* __restrict__ Wmsg,
                                                 const float* __restrict__ Wih,
                                                 const float* __restrict__ Whh,
                                                 unsigned short* __restrict__ Wnk) {
    int n = blockIdx.x;        // 0..511
    int k = threadIdx.x;       // 0..511
    int sec = n >> 7, c = n & 127;
    float v = 0.f;
    if (k < 384) {
        if (sec < 3) {
            int t = k >> 7, kk = k & 127;
            const float* wm = Wmsg + ((long)t * HID + kk) * HID;       // W_msg[t][kk][:]
            const float* wi = Wih + (long)(sec * HID + c) * HID;       // W_ih[sec*128+c][:]
            float s = 0.f;
            for (int j = 0; j < HID; j++) s += wm[j] * wi[j];
            v = s;
        }
    } else {
        int kk = k - 384;
        if (sec == 0)      v = Whh[(long)c * HID + kk];
        else if (sec == 1) v = Whh[(long)(HID + c) * HID + kk];
        else if (sec == 3) v = Whh[(long)(2 * HID + c) * HID + kk];
    }
    Wnk[(long)n * 512 + k] = f2bf(v);
}

__global__ __launch_bounds__(512) void k_build_bias(const float* __restrict__ bih,
                                                    const float* __restrict__ bhh,
                                                    const float* __restrict__ bmsg,
                                                    const float* __restrict__ Wih,
                                                    float* __restrict__ bbig,
                                                    float* __restrict__ Bdeg) {
    int n = threadIdx.x;       // 0..511
    int sec = n >> 7, c = n & 127;
    float b;
    if (sec == 0)      b = bih[c] + bhh[c];
    else if (sec == 1) b = bih[HID + c] + bhh[HID + c];
    else if (sec == 2) b = bih[2 * HID + c];
    else               b = bhh[2 * HID + c];
    bbig[n] = b;
    for (int t = 0; t < 3; t++) {
        float s = 0.f;
        if (sec < 3) {
            const float* wi = Wih + (long)(sec * HID + c) * HID;
            const float* bm = bmsg + t * HID;
            for (int j = 0; j < HID; j++) s += bm[j] * wi[j];
        }
        Bdeg[t * 512 + n] = s;
    }
}

// ---------------------------------------------------------------------------
// Aggregate, MLP-optimized: one WAVE per node. Lane = (g = l>>4 neighbor
// group) x (c16 = l&15 16B chunk). Each short8 load covers 4 neighbors in
// parallel; csr index rows hoisted up front; cross-group reduce via shfl_xor.
// ---------------------------------------------------------------------------
__global__ __launch_bounds__(256) void k_agg(unsigned short* __restrict__ X,
                                             const int* __restrict__ deg,
                                             const int* __restrict__ csr) {
    const int lane = threadIdx.x & 63;
    const long n = (long)blockIdx.x * 4 + (threadIdx.x >> 6);
    const int g = lane >> 4;
    const int c16 = lane & 15;
    const int l31 = lane & 31;

    int d[3], il[3];
#pragma unroll
    for (int t = 0; t < 3; t++) {
        int dt = deg[t * NN + n];
        d[t] = dt > DEG_CAP ? DEG_CAP : dt;
        il[t] = csr[((long)t * NN + n) * DEG_CAP + l31];
    }
#pragma unroll
    for (int t = 0; t < 3; t++) {
        float acc[8] = {0.f, 0.f, 0.f, 0.f, 0.f, 0.f, 0.f, 0.f};
        int rounds = (d[t] + 3) >> 2;
        for (int r = 0; r < rounds; r++) {
            int j = r * 4 + g;
            int idx = __shfl(il[t], j & 31);
            if (j < d[t]) {
                short8 v = *(const short8*)(X + (long)idx * XS + 384 + c16 * 8);
#pragma unroll
                for (int q = 0; q < 8; q++) acc[q] += bf2f((unsigned short)v[q]);
            }
        }
#pragma unroll
        for (int q = 0; q < 8; q++) {
            acc[q] += __shfl_xor(acc[q], 16);
            acc[q] += __shfl_xor(acc[q], 32);
        }
        if (g == 0) {
            short8 o;
#pragma unroll
            for (int q = 0; q < 8; q++) o[q] = (short)f2bf(acc[q]);
            *(short8*)(X + n * XS + t * HID + c16 * 8) = o;
        }
    }
}

// ---------------------------------------------------------------------------
// Fused GRU step: [A_cat|h] (K=512) x Wnk (N=512) MFMA GEMM + gates.
// BM=128, BN=512, BK=32, 8 waves, wave tile 64x128 (2x4 of 32x32).
// LDS swizzle: unit ^= (row>>1)&3  — injects row bits 1..2 (the bits the
// 64B row stride discards from the bank index); row bit 0 contributes via
// 16*(row&1). slot = 4*(row&1) + (u^((row>>1)&3)) is bijective in row bits
// 0..2 -> conflict-free ds_read_b128. (Old row&3 swizzle was 8-way.)
// Epilogue: 8 x 16-row chunks through reused LDS, writes h bf16 into X.
// ---------------------------------------------------------------------------
__global__ __launch_bounds__(512, 2) void k_gru_mfma(
        unsigned short* __restrict__ X, const unsigned short* __restrict__ Wnk,
        const float* __restrict__ bbig, const float* __restrict__ Bdeg,
        const int4* __restrict__ degp) {
    __shared__ char lds[40960];
    char* Al = lds;                 // [128 rows][64 B]
    char* Bl = lds + 8192;          // [512 rows][64 B]

    const int tid = threadIdx.x;
    const int lane = tid & 63;
    const int wv = tid >> 6;
    const int wr = wv >> 2;         // 0..1
    const int wc = wv & 3;          // 0..3
    const int r31 = lane & 31;
    const int kg = lane >> 5;       // 0..1
    const int swr = (r31 >> 1) & 3; // read-side swizzle key
    const long row0 = (long)blockIdx.x * 128;

    f32x16 acc[2][4];
#pragma unroll
    for (int i = 0; i < 2; i++)
#pragma unroll
        for (int j = 0; j < 4; j++) acc[i][j] = (f32x16)(0.0f);

    // staging: thread covers (srow = tid>>2, unit su = tid&3); source swizzled
    const int srow = tid >> 2;
    const int su = tid & 3;
    const int swu = (su ^ ((srow >> 1) & 3)) * 16;
    const char* pA = (const char*)X + (row0 + srow) * 1024 + swu;
    const char* pB = (const char*)Wnk + (long)srow * 1024 + swu;

    float4 pa, pb0, pb1, pb2, pb3;
    pa  = *(const float4*)(pA);
    pb0 = *(const float4*)(pB);
    pb1 = *(const float4*)(pB + 131072);
    pb2 = *(const float4*)(pB + 262144);
    pb3 = *(const float4*)(pB + 393216);

    for (int it = 0; it < 16; it++) {
        __syncthreads();
        *(float4*)(Al + tid * 16)         = pa;
        *(float4*)(Bl + tid * 16)         = pb0;
        *(float4*)(Bl + 8192  + tid * 16) = pb1;
        *(float4*)(Bl + 16384 + tid * 16) = pb2;
        *(float4*)(Bl + 24576 + tid * 16) = pb3;
        if (it < 15) {
            long ko = (long)(it + 1) * 64;
            pa  = *(const float4*)(pA + ko);
            pb0 = *(const float4*)(pB + ko);
            pb1 = *(const float4*)(pB + 131072 + ko);
            pb2 = *(const float4*)(pB + 262144 + ko);
            pb3 = *(const float4*)(pB + 393216 + ko);
        }
        __syncthreads();

        short8 af[2][2], bfr[4][2];
#pragma unroll
        for (int rt = 0; rt < 2; rt++)
#pragma unroll
            for (int kb = 0; kb < 2; kb++)
                af[rt][kb] = *(const short8*)(Al + (wr * 64 + rt * 32 + r31) * 64 +
                                              (((2 * kb + kg) ^ swr) * 16));
#pragma unroll
        for (int ct = 0; ct < 4; ct++)
#pragma unroll
            for (int kb = 0; kb < 2; kb++)
                bfr[ct][kb] = *(const short8*)(Bl + (wc * 128 + ct * 32 + r31) * 64 +
                                               (((2 * kb + kg) ^ swr) * 16));
#pragma unroll
        for (int kb = 0; kb < 2; kb++)
#pragma unroll
            for (int rt = 0; rt < 2; rt++)
#pragma unroll
                for (int ct = 0; ct < 4; ct++)
                    acc[rt][ct] = __builtin_amdgcn_mfma_f32_32x32x16_bf16(
                        __builtin_bit_cast(bf16x8, af[rt][kb]),
                        __builtin_bit_cast(bf16x8, bfr[ct][kb]),
                        acc[rt][ct], 0, 0, 0);
    }

    // ---- epilogue: 8 chunks of 16 rows through LDS exchange ----
    float* EX = (float*)lds;        // [16][512] f32 = 32 KB
#pragma unroll
    for (int ch = 0; ch < 8; ch++) {
        __syncthreads();
        if (wr == (ch >> 2)) {
            const int rt = (ch >> 1) & 1;
            const int half = ch & 1;
#pragma unroll
            for (int ct = 0; ct < 4; ct++) {
                int n = wc * 128 + ct * 32 + r31;
#pragma unroll
                for (int q = 0; q < 8; q++) {
                    int row16 = (q & 3) + 8 * ((q >> 2) & 1) + 4 * kg;
                    EX[row16 * 512 + n] = acc[rt][ct][half * 8 + q];
                }
            }
        }
        __syncthreads();
        {
            int row16 = tid >> 5;
            int c0 = (tid & 31) << 2;
            long grow = row0 + ch * 16 + row16;
            int4 dg = degp[grow];
            float dgx = (float)dg.x, dgy = (float)dg.y, dgz = (float)dg.z;
            const float* ex = EX + row16 * 512;
            float4 vr = *(const float4*)(ex + c0);
            float4 vz = *(const float4*)(ex + 128 + c0);
            float4 vn = *(const float4*)(ex + 256 + c0);
            float4 vh = *(const float4*)(ex + 384 + c0);
            float4 br = *(const float4*)(bbig + c0);
            float4 bz = *(const float4*)(bbig + 128 + c0);
            float4 bn = *(const float4*)(bbig + 256 + c0);
            float4 bh = *(const float4*)(bbig + 384 + c0);
            float4 d00 = *(const float4*)(Bdeg + c0);
            float4 d01 = *(const float4*)(Bdeg + 128 + c0);
            float4 d02 = *(const float4*)(Bdeg + 256 + c0);
            float4 d10 = *(const float4*)(Bdeg + 512 + c0);
            float4 d11 = *(const float4*)(Bdeg + 512 + 128 + c0);
            float4 d12 = *(const float4*)(Bdeg + 512 + 256 + c0);
            float4 d20 = *(const float4*)(Bdeg + 1024 + c0);
            float4 d21 = *(const float4*)(Bdeg + 1024 + 128 + c0);
            float4 d22 = *(const float4*)(Bdeg + 1024 + 256 + c0);
            ushort4 ho = *(const ushort4*)(X + grow * XS + 384 + c0);

            float aR[4] = {vr.x, vr.y, vr.z, vr.w};
            float aZ[4] = {vz.x, vz.y, vz.z, vz.w};
            float aN[4] = {vn.x, vn.y, vn.z, vn.w};
            float aH[4] = {vh.x, vh.y, vh.z, vh.w};
            float bR[4] = {br.x, br.y, br.z, br.w};
            float bZ[4] = {bz.x, bz.y, bz.z, bz.w};
            float bN[4] = {bn.x, bn.y, bn.z, bn.w};
            float bH[4] = {bh.x, bh.y, bh.z, bh.w};
            float e00[4] = {d00.x, d00.y, d00.z, d00.w};
            float e01[4] = {d01.x, d01.y, d01.z, d01.w};
            float e02[4] = {d02.x, d02.y, d02.z, d02.w};
            float e10[4] = {d10.x, d10.y, d10.z, d10.w};
            float e11[4] = {d11.x, d11.y, d11.z, d11.w};
            float e12[4] = {d12.x, d12.y, d12.z, d12.w};
            float e20[4] = {d20.x, d20.y, d20.z, d20.w};
            float e21[4] = {d21.x, d21.y, d21.z, d21.w};
            float e22[4] = {d22.x, d22.y, d22.z, d22.w};
            unsigned short hold[4] = {ho.x, ho.y, ho.z, ho.w};

            ushort4 outp;
            unsigned short* op = (unsigned short*)&outp;
#pragma unroll
            for (int cc = 0; cc < 4; cc++) {
                float Sr = aR[cc] + bR[cc] + dgx * e00[cc] + dgy * e10[cc] + dgz * e20[cc];
                float Sz = aZ[cc] + bZ[cc] + dgx * e01[cc] + dgy * e11[cc] + dgz * e21[cc];
                float In = aN[cc] + bN[cc] + dgx * e02[cc] + dgy * e12[cc] + dgz * e22[cc];
                float Hn = aH[cc] + bH[cc];
                float rr = sigm(Sr);
                float zz = sigm(Sz);
                float tt = In + rr * Hn;
                float e2 = __expf(2.f * tt);
                float nn = 1.f - 2.f / (e2 + 1.f);
                float hv = (1.f - zz) * nn + zz * bf2f(hold[cc]);
                op[cc] = f2bf(hv);
            }
            *(ushort4*)(X + grow * XS + 384 + c0) = outp;
        }
    }
}

// ---------------------------------------------------------------------------
// Readout: out[g] += sigmoid(h@Wg.T+bg) * (h@Wp.T+bp). h from X bf16.
// 32 rows/block, fp32 vector GEMM (tiny FLOPs), block-local rows -> atomics.
// ---------------------------------------------------------------------------
__global__ __launch_bounds__(256) void k_readout(const unsigned short* __restrict__ X,
                                                 const int* __restrict__ n2g,
                                                 const float* __restrict__ Wp,
                                                 const float* __restrict__ bp,
                                                 const float* __restrict__ Wg,
                                                 const float* __restrict__ bg,
                                                 float* __restrict__ out) {
    __shared__ float hs[32][132];
    __shared__ float Ws[64][129];
    int tid = threadIdx.x;
    long row0 = (long)blockIdx.x * 32;
    int rg = tid >> 5, cg = tid & 31;
    float acc[4][4];
#pragma unroll
    for (int r = 0; r < 4; r++)
#pragma unroll
        for (int c = 0; c < 4; c++) acc[r][c] = 0.f;

#pragma unroll
    for (int p = 0; p < 2; p++) {
        int e = p * 256 + tid;
        int r = e >> 4, c8 = e & 15;
        short8 v = *(const short8*)(X + (row0 + r) * XS + 384 + c8 * 8);
#pragma unroll
        for (int j = 0; j < 8; j++) hs[r][c8 * 8 + j] = bf2f((unsigned short)v[j]);
    }
    for (int kc = 0; kc < 128; kc += 64) {
        __syncthreads();
#pragma unroll
        for (int p = 0; p < 8; p++) {
            int idx = p * 256 + tid;
            int j = idx >> 4, q = idx & 15;
            const float* Wsrc = (j < 64) ? Wp : Wg;
            float4 w = *(const float4*)&Wsrc[(j & 63) * HID + kc + q * 4];
            Ws[q * 4 + 0][j] = w.x;
            Ws[q * 4 + 1][j] = w.y;
            Ws[q * 4 + 2][j] = w.z;
            Ws[q * 4 + 3][j] = w.w;
        }
        __syncthreads();
#pragma unroll 8
        for (int k = 0; k < 64; k++) {
            float a[4], w[4];
#pragma unroll
            for (int r = 0; r < 4; r++) a[r] = hs[rg * 4 + r][kc + k];
#pragma unroll
            for (int c = 0; c < 4; c++) w[c] = Ws[k][cg + 32 * c];
#pragma unroll
            for (int r = 0; r < 4; r++)
#pragma unroll
                for (int c = 0; c < 4; c++) acc[r][c] += a[r] * w[c];
        }
    }
#pragma unroll
    for (int r = 0; r < 4; r++) {
        long row = row0 + rg * 4 + r;
        if (row < NN) {
            int g = n2g[row];
            float pv0 = acc[r][0] + bp[cg];
            float pv1 = acc[r][1] + bp[cg + 32];
            float gv0 = acc[r][2] + bg[cg];
            float gv1 = acc[r][3] + bg[cg + 32];
            atomicAdd(&out[g * EMB + cg],      pv0 * sigm(gv0));
            atomicAdd(&out[g * EMB + cg + 32], pv1 * sigm(gv1));
        }
    }
}

// ---------------------------------------------------------------------------
extern "C" void kernel_launch(void* const* d_in, const int* in_sizes, int n_in,
                              void* d_out, int out_size, void* d_ws, size_t ws_size,
                              hipStream_t stream) {
    const float* node_features = (const float*)d_in[0];
    const int*   edge_index    = (const int*)d_in[1];
    const int*   n2g           = (const int*)d_in[2];
    const float* W_msg         = (const float*)d_in[3];
    const float* b_msg         = (const float*)d_in[4];
    const float* W_ih          = (const float*)d_in[5];
    const float* W_hh          = (const float*)d_in[6];
    const float* b_ih          = (const float*)d_in[7];
    const float* b_hh          = (const float*)d_in[8];
    const float* W_proj        = (const float*)d_in[9];
    const float* b_proj        = (const float*)d_in[10];
    const float* W_gate        = (const float*)d_in[11];
    const float* b_gate        = (const float*)d_in[12];

    char* ws = (char*)d_ws;
    unsigned short* X    = (unsigned short*)(ws);                 // 102,498,304 B
    unsigned short* Wnk  = (unsigned short*)(ws + 102498304);     //    524,288 B
    float*          bbig = (float*)         (ws + 103022592);     //      2,048 B
    float*          Bdeg = (float*)         (ws + 103024640);     //      6,144 B
    int4*           degp = (int4*)          (ws + 103030784);     //  1,601,536 B
    int*            deg  = (int*)           (ws + 104632320);     //  1,200,000 B
    int*            csr  = (int*)           (ws + 105832320);     // 38,400,000 B -> 144,232,320

    float* out = (float*)d_out;

    hipMemsetAsync(out, 0, (size_t)NG * EMB * sizeof(float), stream);
    hipMemsetAsync(deg, 0, (size_t)3 * NN * sizeof(int), stream);

    k_init<<<dim3((NN * HID) / 256), dim3(256), 0, stream>>>(node_features, X);
    k_build_csr<<<dim3((3 * NE + 255) / 256), dim3(256), 0, stream>>>(edge_index, deg, csr);
    k_pack_deg<<<dim3(NNP / 256), dim3(256), 0, stream>>>(deg, degp);
    k_build_w<<<dim3(512), dim3(512), 0, stream>>>(W_msg, W_ih, W_hh, Wnk);
    k_build_bias<<<dim3(1), dim3(512), 0, stream>>>(b_ih, b_hh, b_msg, W_ih, bbig, Bdeg);

    for (int step = 0; step < 4; step++) {
        k_agg<<<dim3(NN / 4), dim3(256), 0, stream>>>(X, deg, csr);
        k_gru_mfma<<<dim3(NNP / 128), dim3(512), 0, stream>>>(X, Wnk, bbig, Bdeg, degp);
    }
    k_readout<<<dim3(NN / 32), dim3(256), 0, stream>>>(X, n2g, W_proj, b_proj,
                                                       W_gate, b_gate, out);
}